// Round 10
// baseline (440.771 us; speedup 1.0000x reference)
//
#include <hip/hip_runtime.h>
#include <hip/hip_bf16.h>

#define DM 256
#define NH 8
#define DK 32
#define BSZ 2
#define SEQ 2048
#define ROWS (BSZ*SEQ)   // 4096
#define RT 16            // query rows per attention tile (full MFMA rows)
#define SRBH 1144        // attn3 half-buffer row stride (1024 cols: max phys 1143)
#define SRBW 1160        // attn12 window row stride (1024 cols; 2-way-free PV banks)

static __device__ __forceinline__ int sw8(int j) { return j + ((j >> 6) << 3); }

typedef __attribute__((ext_vector_type(8))) short short8;
typedef __attribute__((ext_vector_type(4))) float f32x4;

// f32 -> bf16 bits, round-to-nearest-even (validated r15)
static __device__ __forceinline__ unsigned short f2bf(float f) {
    unsigned u = __float_as_uint(f);
    return (unsigned short)((u + 0x7FFFu + ((u >> 16) & 1u)) >> 16);
}
static __device__ __forceinline__ float bf2f(unsigned short h) {
    return __uint_as_float(((unsigned)h) << 16);
}

// packed f32x2 -> bf16x2 (RNE), single HW instr
static __device__ __forceinline__ unsigned cvtpk(float lo, float hi) {
    unsigned r;
    asm("v_cvt_pk_bf16_f32 %0, %1, %2" : "=v"(r) : "v"(lo), "v"(hi));
    return r;
}

// native transcendentals: inputs range-safe (underflow-to-zero desired).
static __device__ __forceinline__ float ex2(float x) { return __builtin_amdgcn_exp2f(x); }
static __device__ __forceinline__ float sqt(float x) { return __builtin_amdgcn_sqrtf(x); }
static __device__ __forceinline__ float rcp(float x) { return __builtin_amdgcn_rcpf(x); }

// ---- DPP cross-lane (VALU-pipe) ----
template<int CTRL, int RM>
static __device__ __forceinline__ float dppadd(float x) {
    int s = __builtin_amdgcn_update_dpp(0, __float_as_int(x), CTRL, RM, 0xf, true);
    return x + __int_as_float(s);
}
// inclusive prefix sum over each 32-lane group
static __device__ __forceinline__ float scan32(float x) {
    x = dppadd<0x111, 0xf>(x);   // row_shr:1
    x = dppadd<0x112, 0xf>(x);   // row_shr:2
    x = dppadd<0x114, 0xf>(x);   // row_shr:4
    x = dppadd<0x118, 0xf>(x);   // row_shr:8
    x = dppadd<0x142, 0xa>(x);   // row_bcast15, rows 1&3
    return x;
}
// inclusive prefix sum over each 16-lane group (VALU pipe only)
static __device__ __forceinline__ float scan16(float x) {
    x = dppadd<0x111, 0xf>(x);   // row_shr:1
    x = dppadd<0x112, 0xf>(x);   // row_shr:2
    x = dppadd<0x114, 0xf>(x);   // row_shr:4
    x = dppadd<0x118, 0xf>(x);   // row_shr:8
    return x;
}
// sum over each 16-lane group, result in every lane
static __device__ __forceinline__ float red16(float x) {
    x = dppadd<0x0B1, 0xf>(x);   // quad_perm xor1
    x = dppadd<0x04E, 0xf>(x);   // quad_perm xor2
    x = dppadd<0x124, 0xf>(x);   // row_ror:4
    x = dppadd<0x128, 0xf>(x);   // row_ror:8
    return x;
}
// broadcast lane31 of each 32-group to all its lanes
static __device__ __forceinline__ float bcast31(float x) {
    return __int_as_float(__builtin_amdgcn_ds_swizzle(__float_as_int(x), 0x03E0));
}
// broadcast lane15 of each 16-group to all its lanes
static __device__ __forceinline__ float bcast15(float x) {
    return __int_as_float(__builtin_amdgcn_ds_swizzle(__float_as_int(x), 0x01F0));
}
// lane ^ 16 within each 32-group
static __device__ __forceinline__ float swz_x16(float x) {
    return __int_as_float(__builtin_amdgcn_ds_swizzle(__float_as_int(x), 0x401F));
}

#define MFMA_BF16 __builtin_amdgcn_mfma_f32_16x16x32_bf16
#define LOG2E 1.44269504088896340736f

// ---------- reduction helpers ----------
static __device__ __forceinline__ float waveRedSum(float v) {
    #pragma unroll
    for (int off = 32; off > 0; off >>= 1) v += __shfl_down(v, off, 64);
    return v;
}

// ---------- one-time: weights -> split-bf16, transposed [n][k] ------------
__global__ __launch_bounds__(256) void convert_w_kernel(
    const float* __restrict__ S0, const float* __restrict__ S1, const float* __restrict__ S2,
    const float* __restrict__ S3, const float* __restrict__ S4, const float* __restrict__ S5,
    const float* __restrict__ S6, const float* __restrict__ S7, const float* __restrict__ S8,
    unsigned short* __restrict__ dst,
    const float* __restrict__ know,
    const float* __restrict__ W3q, const float* __restrict__ b3q,
    const float* __restrict__ lkW, const float* __restrict__ lkb,
    float* __restrict__ q3row, float* __restrict__ key8)
{
    __shared__ float kn[DM];
    int s = blockIdx.y;
    if (s == 9) {
        if (blockIdx.x != 0) return;
        int t = threadIdx.x;
        kn[t] = know[t];
        __syncthreads();
        float acc = b3q[t];
        for (int c = 0; c < DM; ++c) acc += kn[c] * W3q[(size_t)c * DM + t];
        q3row[t] = acc;
        float bk = lkb[t];
        for (int h = 0; h < NH; ++h) {
            float a = bk;
            #pragma unroll
            for (int c = 0; c < DK; ++c) a += kn[h * DK + c] * lkW[(size_t)c * DM + t];
            key8[(size_t)h * DM + t] = 1.f / (1.f + __expf(-a));
        }
        return;
    }
    const float* W;
    if (s == 0) W = S0; else if (s == 1) W = S1; else if (s == 2) W = S2;
    else if (s == 3) W = S3; else if (s == 4) W = S4; else if (s == 5) W = S5;
    else if (s == 6) W = S6; else if (s == 7) W = S7; else W = S8;
    unsigned short* H = dst + (size_t)s * 131072;
    unsigned short* L = H + 65536;

    int e = blockIdx.x * 1024 + threadIdx.x * 4;
    int k = e >> 8, n = e & 255;
    float4 w4 = *(const float4*)(W + e);
    float v[4] = {w4.x, w4.y, w4.z, w4.w};
    #pragma unroll
    for (int i = 0; i < 4; ++i) {
        unsigned short h = f2bf(v[i]);
        H[(size_t)(n + i) * 256 + k] = h;
        L[(size_t)(n + i) * 256 + k] = (unsigned short)f2bf(v[i] - bf2f(h));
    }
}

// ---------- batched MFMA GEMM (16x256/block, 4 sets) with optional ----------
// split-bf16 side outputs: KSo = [row][col] hi/lo; VSo = [col][row] hi only.
__global__ __launch_bounds__(256) void gemm4_kernel(
    const float* __restrict__ X0, const unsigned short* __restrict__ H0, const float* __restrict__ B0,
    float* __restrict__ Y0, unsigned short* __restrict__ K0o, unsigned short* __restrict__ V0o,
    const float* __restrict__ X1, const unsigned short* __restrict__ H1, const float* __restrict__ B1,
    float* __restrict__ Y1, unsigned short* __restrict__ K1o, unsigned short* __restrict__ V1o,
    const float* __restrict__ X2, const unsigned short* __restrict__ H2, const float* __restrict__ B2,
    float* __restrict__ Y2, unsigned short* __restrict__ K2o, unsigned short* __restrict__ V2o,
    const float* __restrict__ X3, const unsigned short* __restrict__ H3, const float* __restrict__ B3,
    float* __restrict__ Y3, unsigned short* __restrict__ K3o, unsigned short* __restrict__ V3o)
{
    const float *X, *Bias; const unsigned short* H; float* Yf;
    unsigned short *KSo, *VSo;
    int s = blockIdx.y;
    if (s == 0)      { X = X0; H = H0; Bias = B0; Yf = Y0; KSo = K0o; VSo = V0o; }
    else if (s == 1) { X = X1; H = H1; Bias = B1; Yf = Y1; KSo = K1o; VSo = V1o; }
    else if (s == 2) { X = X2; H = H2; Bias = B2; Yf = Y2; KSo = K2o; VSo = V2o; }
    else             { X = X3; H = H3; Bias = B3; Yf = Y3; KSo = K3o; VSo = V3o; }
    const unsigned short* L = H + 65536;

    __shared__ __align__(16) unsigned short XhL[16 * 264];
    __shared__ __align__(16) unsigned short XlL[16 * 264];
    __shared__ __align__(16) unsigned short vt[256][24];   // V^T staging
    int t = threadIdx.x;
    int r0 = blockIdx.x * 16;
    {   // stage X tile as split bf16
        int r = t >> 4, c0 = (t & 15) * 16;
        const float* xp = X + (size_t)(r0 + r) * DM + c0;
        #pragma unroll
        for (int i = 0; i < 16; i += 4) {
            float4 v4 = *(const float4*)(xp + i);
            float vv[4] = {v4.x, v4.y, v4.z, v4.w};
            #pragma unroll
            for (int j = 0; j < 4; ++j) {
                unsigned short h = f2bf(vv[j]);
                XhL[r * 264 + c0 + i + j] = h;
                XlL[r * 264 + c0 + i + j] = (unsigned short)f2bf(vv[j] - bf2f(h));
            }
        }
    }
    __syncthreads();
    int lane = t & 63, wv = t >> 6;
    int m = lane & 15, quad = lane >> 4;
    f32x4 aa[4];
    #pragma unroll
    for (int nt = 0; nt < 4; ++nt) { aa[nt][0]=0.f; aa[nt][1]=0.f; aa[nt][2]=0.f; aa[nt][3]=0.f; }
    #pragma unroll 1
    for (int kc = 0; kc < 8; ++kc) {
        int k0 = kc * 32;
        short8 Ah = *(const short8*)&XhL[m * 264 + k0 + quad * 8];
        short8 Al = *(const short8*)&XlL[m * 264 + k0 + quad * 8];
        size_t boff = (size_t)(wv * 64 + m) * 256 + k0 + quad * 8;
        #pragma unroll
        for (int nt = 0; nt < 4; ++nt) {
            short8 Bh = *(const short8*)(H + boff + nt * 16 * 256);
            short8 Bl = *(const short8*)(L + boff + nt * 16 * 256);
            aa[nt] = MFMA_BF16(Al, Bh, aa[nt], 0, 0, 0);
            aa[nt] = MFMA_BF16(Ah, Bl, aa[nt], 0, 0, 0);
            aa[nt] = MFMA_BF16(Ah, Bh, aa[nt], 0, 0, 0);
        }
    }
    // epilogue: D col = lane&15 (+16*nt +64*wv), row = quad*4+g
    int col0 = wv * 64 + m;
    #pragma unroll
    for (int nt = 0; nt < 4; ++nt) {
        int col = col0 + nt * 16;
        float bb = Bias[col];
        float yv[4];
        #pragma unroll
        for (int g = 0; g < 4; ++g) yv[g] = aa[nt][g] + bb;
        if (Yf) {
            #pragma unroll
            for (int g = 0; g < 4; ++g)
                Yf[(size_t)(r0 + quad * 4 + g) * DM + col] = yv[g];
        }
        if (KSo) {
            unsigned short* KH = KSo;
            unsigned short* KL = KSo + (size_t)ROWS * DM;
            #pragma unroll
            for (int g = 0; g < 4; ++g) {
                unsigned short hb = f2bf(yv[g]);
                KH[(size_t)(r0 + quad * 4 + g) * DM + col] = hb;
                KL[(size_t)(r0 + quad * 4 + g) * DM + col] =
                    (unsigned short)f2bf(yv[g] - bf2f(hb));
            }
        }
        if (VSo) {
            ushort4 h4;
            h4.x = f2bf(yv[0]); h4.y = f2bf(yv[1]);
            h4.z = f2bf(yv[2]); h4.w = f2bf(yv[3]);
            *(ushort4*)&vt[col][quad * 4] = h4;
        }
    }
    if (VSo) {
        __syncthreads();
        short8 v0 = *(const short8*)&vt[t][0];
        short8 v1 = *(const short8*)&vt[t][8];
        unsigned short* vp = VSo + (size_t)t * ROWS + r0;
        *(short8*)vp = v0;
        *(short8*)(vp + 8) = v1;
    }
}

// ---------- MFMA GEMM + residual + LayerNorm fused (2 sets) ----------
__global__ __launch_bounds__(256) void gemm_ln2_kernel(
    const float* __restrict__ X0, const unsigned short* __restrict__ H0, const float* __restrict__ B0,
    const float* __restrict__ R0, const float* __restrict__ G0, const float* __restrict__ L0,
    float* __restrict__ Y0, int bc0,
    const float* __restrict__ X1, const unsigned short* __restrict__ H1, const float* __restrict__ B1,
    const float* __restrict__ R1, const float* __restrict__ G1, const float* __restrict__ L1,
    float* __restrict__ Y1, int bc1)
{
    const float *X, *Bias, *R, *G, *Lb; const unsigned short* H; float* Y; int bc;
    if (blockIdx.y == 0) { X=X0; H=H0; Bias=B0; R=R0; G=G0; Lb=L0; Y=Y0; bc=bc0; }
    else                 { X=X1; H=H1; Bias=B1; R=R1; G=G1; Lb=L1; Y=Y1; bc=bc1; }
    const unsigned short* L = H + 65536;

    __shared__ __align__(16) unsigned short XhL[16 * 264];
    __shared__ __align__(16) unsigned short XlL[16 * 264];
    __shared__ __align__(16) float yl[16 * 260];
    int t = threadIdx.x;
    int r0 = blockIdx.x * 16;
    {   int r = t >> 4, c0 = (t & 15) * 16;
        const float* xp = X + (size_t)(r0 + r) * DM + c0;
        #pragma unroll
        for (int i = 0; i < 16; i += 4) {
            float4 v4 = *(const float4*)(xp + i);
            float vv[4] = {v4.x, v4.y, v4.z, v4.w};
            #pragma unroll
            for (int j = 0; j < 4; ++j) {
                unsigned short h = f2bf(vv[j]);
                XhL[r * 264 + c0 + i + j] = h;
                XlL[r * 264 + c0 + i + j] = (unsigned short)f2bf(vv[j] - bf2f(h));
            }
        }
    }
    __syncthreads();
    int lane = t & 63, wv = t >> 6;
    int m = lane & 15, quad = lane >> 4;
    f32x4 aa[4];
    #pragma unroll
    for (int nt = 0; nt < 4; ++nt) { aa[nt][0]=0.f; aa[nt][1]=0.f; aa[nt][2]=0.f; aa[nt][3]=0.f; }
    #pragma unroll 1
    for (int kc = 0; kc < 8; ++kc) {
        int k0 = kc * 32;
        short8 Ah = *(const short8*)&XhL[m * 264 + k0 + quad * 8];
        short8 Al = *(const short8*)&XlL[m * 264 + k0 + quad * 8];
        size_t boff = (size_t)(wv * 64 + m) * 256 + k0 + quad * 8;
        #pragma unroll
        for (int nt = 0; nt < 4; ++nt) {
            short8 Bh = *(const short8*)(H + boff + nt * 16 * 256);
            short8 Bl = *(const short8*)(L + boff + nt * 16 * 256);
            aa[nt] = MFMA_BF16(Al, Bh, aa[nt], 0, 0, 0);
            aa[nt] = MFMA_BF16(Ah, Bl, aa[nt], 0, 0, 0);
            aa[nt] = MFMA_BF16(Ah, Bh, aa[nt], 0, 0, 0);
        }
    }
    {
        int col0 = wv * 64 + m;
        #pragma unroll
        for (int nt = 0; nt < 4; ++nt) {
            int col = col0 + nt * 16;
            float bb = Bias[col];
            #pragma unroll
            for (int g = 0; g < 4; ++g) {
                int row = quad * 4 + g;
                float res = bc ? R[col] : R[(size_t)(r0 + row) * DM + col];
                yl[row * 260 + col] = aa[nt][g] + bb + res;
            }
        }
    }
    __syncthreads();
    {
        int r = t >> 4, c0 = (t & 15) * 16;
        float vals[16];
        float part = 0.f;
        #pragma unroll
        for (int i = 0; i < 16; ++i) { vals[i] = yl[r * 260 + c0 + i]; part += vals[i]; }
        #pragma unroll
        for (int off = 8; off; off >>= 1) part += __shfl_xor(part, off, 16);
        float mean = part * (1.f / DM);
        float vp = 0.f;
        #pragma unroll
        for (int i = 0; i < 16; ++i) { float d = vals[i] - mean; vp += d * d; }
        #pragma unroll
        for (int off = 8; off; off >>= 1) vp += __shfl_xor(vp, off, 16);
        float rs = rsqrtf(vp * (1.f / DM) + 1e-5f);
        float* yp = Y + (size_t)(r0 + r) * DM + c0;
        #pragma unroll
        for (int i = 0; i < 16; i += 4) {
            float4 o;
            o.x = (vals[i+0] - mean) * rs * G[c0+i+0] + Lb[c0+i+0];
            o.y = (vals[i+1] - mean) * rs * G[c0+i+1] + Lb[c0+i+1];
            o.z = (vals[i+2] - mean) * rs * G[c0+i+2] + Lb[c0+i+2];
            o.w = (vals[i+3] - mean) * rs * G[c0+i+3] + Lb[c0+i+3];
            *(float4*)(yp + i) = o;
        }
    }
}

// ---------- attn3 scores, parallel: 128 blocks (8 j-slices x 16 bh) --------
__global__ __launch_bounds__(256) void score3a_kernel(
    const float* __restrict__ q3row, const float* __restrict__ K3,
    unsigned short* __restrict__ S3, float* __restrict__ C3,
    float* __restrict__ Csum)
{
    __shared__ float wsum[4];
    int s = blockIdx.x;            // j slice (0..7)
    int bh = blockIdx.y;           // b*8+h
    int b = bh >> 3, h = bh & 7;
    int t = threadIdx.x;
    int lane = t & 63, wv = t >> 6;
    int j = s * 256 + t;
    const float scaleL2 = 0.17677669529663687f * LOG2E;
    float qv[DK];
    #pragma unroll
    for (int d = 0; d < DK; d += 4) {
        float4 qq = *(const float4*)(q3row + h * DK + d);
        qv[d+0] = qq.x * scaleL2; qv[d+1] = qq.y * scaleL2;
        qv[d+2] = qq.z * scaleL2; qv[d+3] = qq.w * scaleL2;
    }
    const float* kp = K3 + ((size_t)b * SEQ + j) * DM + h * DK;
    float kv[DK];
    #pragma unroll
    for (int d = 0; d < DK; d += 4) {
        float4 kq = *(const float4*)(kp + d);
        kv[d+0] = kq.x; kv[d+1] = kq.y; kv[d+2] = kq.z; kv[d+3] = kq.w;
    }
    float sc = 0.f;
    #pragma unroll
    for (int d = 0; d < DK; ++d) sc += qv[d] * kv[d];
    unsigned short sb16 = f2bf(sc);
    float e = ex2(bf2f(sb16));
    float x = e;
    #pragma unroll
    for (int off = 1; off < 64; off <<= 1) {
        float y = __shfl_up(x, off, 64);
        if (lane >= off) x += y;
    }
    if (lane == 63) wsum[wv] = x;
    __syncthreads();
    float woff = 0.f;
    for (int w = 0; w < wv; ++w) woff += wsum[w];
    float inc = woff + x;
    S3[(size_t)bh * SEQ + j] = sb16;
    C3[(size_t)bh * SEQ + j] = inc;
    if (t == 255) Csum[bh * 8 + s] = inc;
}

// fix-up: add exclusive slice offsets so C3 is row-global inclusive.
__global__ __launch_bounds__(256) void score3b_kernel(
    const float* __restrict__ Csum, float* __restrict__ C3)
{
    int s = blockIdx.x + 1;        // slices 1..7
    int bh = blockIdx.y;
    int t = threadIdx.x;
    float off = 0.f;
    for (int w = 0; w < s; ++w) off += Csum[bh * 8 + w];
    C3[(size_t)bh * SEQ + s * 256 + t] += off;
}

// ---------- blocks 1+2 attention v2: register scores + windowed P ----------
// r10 redesign: phase 1 keeps scores packed bf16 in 32 VGPRs (NO score LDS);
// per-32-col-block exp2 totals -> ct[16][64] (4KB); one cooperative scan gives
// exclusive prefixes + row totals l. Pass C runs on registers with DPP scan16
// and writes P into a 1024-col window buffer; PV consumes each window before
// the next overwrites it. LDS 76.8K -> ~42K => 3 blocks/CU (24 waves, 1.5x).
// Window size 1024 is a multiple of 256 so PV's per-wave j-sequence and all
// accumulation orders match the monolithic version exactly (r3 numerics).
__global__ __launch_bounds__(512) void attn12_kernel(
    const float* __restrict__ Q0,
    const unsigned short* __restrict__ KS0, const unsigned short* __restrict__ VS0,
    const float* __restrict__ g0, float* __restrict__ O0,
    const float* __restrict__ Q1,
    const unsigned short* __restrict__ KS1, const unsigned short* __restrict__ VS1,
    const float* __restrict__ g1, float* __restrict__ O1)
{
    __shared__ __align__(16) unsigned short PB[RT * SRBW];  // 37,120 B (P window / FS)
    __shared__ float ct[16 * 64];                           // 4 KB block prefixes
    __shared__ float l_s[16];
    __shared__ float wl2[8][16];

    // XCD swizzle (gridDim == (128, 32))
    int bx, by;
    {
        int flat = (int)blockIdx.y * 128 + (int)blockIdx.x;
        int per = (32 * 128) >> 3;     // 512 blocks per XCD
        int nf = (flat & 7) * per + (flat >> 3);
        by = nf >> 7;
        bx = nf & 127;
    }
    int set = by >> 4, bh = by & 15;
    const float* Q = set ? Q1 : Q0;
    const unsigned short* KS = set ? KS1 : KS0;
    const unsigned short* VS = set ? VS1 : VS0;
    const float* gm = set ? g1 : g0;
    float* O = set ? O1 : O0;

    int b = bh >> 3, h = bh & 7;
    int i0 = (127 - bx) * RT;          // largest-first within each XCD
    int t = threadIdx.x;
    int wave = t >> 6, lane = t & 63;
    int m = lane & 15, quad = lane >> 4;
    size_t base = ((size_t)b * SEQ) * DM + (size_t)h * DK;
    size_t rowb = (size_t)b * SEQ;

    int njAll = i0 + RT;               // peek=1; multiple of 16
    int nChunks = njAll >> 4;          // 16-col chunks, 1..128
    int nb32 = (nChunks + 1) >> 1;     // 32-col blocks, 1..64
    int njPad32 = nb32 << 5;

    const float scaleL2 = 0.17677669529663687f * LOG2E;

    // Q fragment: row = m, k = quad*8..+8 (hi bf16, scaled)
    short8 Ah;
    {
        const float* qp = Q + base + (size_t)(i0 + m) * DM + quad * 8;
        float4 qa = *(const float4*)qp;
        float4 qb = *(const float4*)(qp + 4);
        float av[8] = {qa.x, qa.y, qa.z, qa.w, qb.x, qb.y, qb.z, qb.w};
        #pragma unroll
        for (int i = 0; i < 8; ++i) Ah[i] = (short)f2bf(av[i] * scaleL2);
    }

    const unsigned short* KH = KS;
    const unsigned short* KL = KS + (size_t)ROWS * DM;
    int njr[4];
    #pragma unroll
    for (int g = 0; g < 4; ++g) njr[g] = i0 + quad * 4 + g + 1;

    unsigned spk[32];   // packed bf16 scores: [bb*4 + half*2 + k]

    // ---- Phase 1: MFMA scores -> regs; masked exp2 block totals -> ct ----
    #pragma unroll
    for (int bb = 0; bb < 8; ++bb) {
        int blk = wave + bb * 8;
        if (blk < nb32) {
            float ctv[4] = {0.f, 0.f, 0.f, 0.f};
            #pragma unroll
            for (int half = 0; half < 2; ++half) {
                int c = blk * 2 + half;
                if (c < nChunks) {
                    int j0 = c << 4;
                    size_t off = (rowb + j0 + m) * DM + h * DK + quad * 8;
                    short8 Bh = *(const short8*)&KH[off];
                    short8 Bl = *(const short8*)&KL[off];
                    f32x4 acc = {0.f, 0.f, 0.f, 0.f};
                    acc = MFMA_BF16(Ah, Bl, acc, 0, 0, 0);
                    acc = MFMA_BF16(Ah, Bh, acc, 0, 0, 0);
                    int jcol = j0 + m;
                    unsigned short u0 = f2bf(acc[0]), u1 = f2bf(acc[1]);
                    unsigned short u2 = f2bf(acc[2]), u3 = f2bf(acc[3]);
                    spk[bb * 4 + half * 2 + 0] = (unsigned)u0 | ((unsigned)u1 << 16);
                    spk[bb * 4 + half * 2 + 1] = (unsigned)u2 | ((unsigned)u3 << 16);
                    // totals from the rounded scores (exactly what pass C uses)
                    ctv[0] += (jcol < njr[0]) ? ex2(bf2f(u0)) : 0.f;
                    ctv[1] += (jcol < njr[1]) ? ex2(bf2f(u1)) : 0.f;
                    ctv[2] += (jcol < njr[2]) ? ex2(bf2f(u2)) : 0.f;
                    ctv[3] += (jcol < njr[3]) ? ex2(bf2f(u3)) : 0.f;
                }
            }
            #pragma unroll
            for (int g = 0; g < 4; ++g) ctv[g] = red16(ctv[g]);
            if (m == 0) {
                #pragma unroll
                for (int g = 0; g < 4; ++g) ct[(quad * 4 + g) * 64 + blk] = ctv[g];
            }
        }
    }
    __syncthreads();

    // ---- cooperative exclusive scan over 32-col blocks (per row) ----
    {
        int r = t >> 5, c0 = t & 31;
        float v0 = (2 * c0     < nb32) ? ct[r * 64 + 2 * c0]     : 0.f;
        float v1 = (2 * c0 + 1 < nb32) ? ct[r * 64 + 2 * c0 + 1] : 0.f;
        float loc = v0 + v1;
        float x = scan32(loc);
        float tot = bcast31(x);
        float excl = x - loc;
        float2 pr; pr.x = excl; pr.y = excl + v0;
        *(float2*)&ct[r * 64 + 2 * c0] = pr;
        if (c0 == 0) l_s[r] = tot;
    }
    __syncthreads();

    float gamma2 = -log1pf(__expf(gm[h])) * LOG2E;
    float linv[4], rowc[4], l2[4];
    #pragma unroll
    for (int g = 0; g < 4; ++g) {
        linv[g] = rcp(l_s[quad * 4 + g]);
        rowc[g] = (float)(i0 + quad * 4 + g - m);
        l2[g] = 0.f;
    }

    size_t vb0 = (size_t)(h * DK + m) * ROWS + rowb;
    size_t vb1 = vb0 + (size_t)16 * ROWS;
    f32x4 oc0 = {0.f,0.f,0.f,0.f}, oc1 = {0.f,0.f,0.f,0.f};

    // ---- windows: pass C (registers -> P window) then PV, twice ----
    #pragma unroll
    for (int q = 0; q < 2; ++q) {
        if (q * 1024 < njPad32) {
            #pragma unroll
            for (int j = 0; j < 4; ++j) {
                int bb = q * 4 + j;
                int blk = wave + bb * 8;
                if (blk < nb32) {
                    float pre[4];
                    #pragma unroll
                    for (int g = 0; g < 4; ++g) pre[g] = ct[(quad * 4 + g) * 64 + blk];
                    #pragma unroll
                    for (int half = 0; half < 2; ++half) {
                        int c = blk * 2 + half;
                        int j0 = c << 4;
                        int lc0 = j0 - q * 1024;
                        int sbase = lc0 + ((lc0 >> 6) << 3);
                        unsigned short* Srow = PB + sbase + m;
                        if (c < nChunks) {
                            int jcol = j0 + m;
                            unsigned pk0 = spk[bb * 4 + half * 2 + 0];
                            unsigned pk1 = spk[bb * 4 + half * 2 + 1];
                            float s[4];
                            s[0] = bf2f((unsigned short)pk0);
                            s[1] = bf2f((unsigned short)(pk0 >> 16));
                            s[2] = bf2f((unsigned short)pk1);
                            s[3] = bf2f((unsigned short)(pk1 >> 16));
                            float x[4];
                            #pragma unroll
                            for (int g = 0; g < 4; ++g)
                                x[g] = (jcol < njr[g]) ? ex2(s[g]) : 0.f;
                            #pragma unroll
                            for (int g = 0; g < 4; ++g) x[g] = scan16(x[g]);
                            #pragma unroll
                            for (int g = 0; g < 4; ++g) {
                                float cum = pre[g] + x[g];
                                float pbv = rowc[g] - (float)j0;
                                float d2 = fmaxf((1.f - cum * linv[g]) * pbv, 0.f);
                                float eff = fmaxf(ex2(sqt(d2) * gamma2), 1e-5f);
                                float p = (jcol < njr[g]) ? ex2(s[g] * eff) : 0.f;
                                l2[g] += p;
                                Srow[(quad * 4 + g) * SRBW] = f2bf(p);
                            }
                            if (half == 0) {
                                #pragma unroll
                                for (int g = 0; g < 4; ++g) pre[g] += bcast15(x[g]);
                            }
                        } else {
                            // pad chunk (nChunks odd): P = 0
                            #pragma unroll
                            for (int g = 0; g < 4; ++g)
                                Srow[(quad * 4 + g) * SRBW] = 0;
                        }
                    }
                }
            }
            __syncthreads();
            // ---- PV on this window ----
            int pend = min((q + 1) * 1024, njPad32);
            #pragma unroll 1
            for (int j0 = q * 1024 + wave * 32; j0 < pend; j0 += 256) {
                int lj = j0 - q * 1024 + quad * 8;
                short8 Ap = *(const short8*)&PB[m * SRBW + lj + ((lj >> 6) << 3)];
                int jo = j0 + quad * 8;
                short8 Bh0 = *(const short8*)&VS[vb0 + jo];
                short8 Bh1 = *(const short8*)&VS[vb1 + jo];
                oc0 = MFMA_BF16(Ap, Bh0, oc0, 0, 0, 0);
                oc1 = MFMA_BF16(Ap, Bh1, oc1, 0, 0, 0);
            }
            __syncthreads();
        }
    }

    // ---- publish l2 partials + O epilogue (PB reused as f32) ----
    #pragma unroll
    for (int g = 0; g < 4; ++g) l2[g] = red16(l2[g]);
    if (m == 0) {
        #pragma unroll
        for (int g = 0; g < 4; ++g) wl2[wave][quad * 4 + g] = l2[g];
    }
    float* FS = (float*)PB;
    #pragma unroll
    for (int g = 0; g < 4; ++g) {
        int row = quad * 4 + g;
        FS[wave * 512 + row * 32 + m] = oc0[g];
        FS[wave * 512 + row * 32 + 16 + m] = oc1[g];
    }
    __syncthreads();
    {
        int r2 = t >> 5, d = t & 31;
        float sum = 0.f, lt = 0.f;
        #pragma unroll
        for (int w = 0; w < 8; ++w) {
            sum += FS[w * 512 + r2 * 32 + d];
            lt += wl2[w][r2];
        }
        O[base + (size_t)(i0 + r2) * DM + d] = sum * rcp(lt);
    }
}

// ---------- attn3 (qbcast path), half-buffered P staging ----------
__global__ __launch_bounds__(512) void attn3_kernel(
    const unsigned short* __restrict__ VS, const float* __restrict__ gm8,
    float* __restrict__ O,
    const unsigned short* __restrict__ S3g, const float* __restrict__ C3g)
{
    __shared__ __align__(16) unsigned short SBH[RT * SRBH];
    __shared__ float l2inv_s[RT];

    // XCD swizzle (gridDim == (128, 16))
    int bx, by;
    {
        int flat = (int)blockIdx.y * 128 + (int)blockIdx.x;
        int per = (16 * 128) >> 3;     // 256 blocks per XCD
        int nf = (flat & 7) * per + (flat >> 3);
        by = nf >> 7;
        bx = nf & 127;
    }
    int bh = by;
    int b = bh >> 3, h = bh & 7;
    int i0 = (127 - bx) * RT;          // largest-first within each XCD
    int t = threadIdx.x;
    size_t base = ((size_t)b * SEQ) * DM + (size_t)h * DK;

    int njAll = i0 + RT - 1;           // peek=0
    int njPad32 = (njAll + 31) & ~31;
    int E = ((njPad32 + 127) >> 7) << 7;   // pass-C extent (multiple of 128)

    int r = t >> 5, c = t & 31;
    int i = i0 + r;
    int nj = i;
    unsigned short* Sr = SBH + r * SRBH;
    float gamma2 = -log1pf(__expf(gm8[h])) * LOG2E;
    const unsigned short* s3p = S3g + (size_t)bh * SEQ;
    const float* c3p = C3g + (size_t)bh * SEQ;
    float Lc = (nj > 0) ? c3p[nj - 1] : 0.f;
    float linv = (nj > 0) ? rcp(Lc) : 0.f;
    float li2 = linv + linv, li3 = li2 + linv;
    float l2 = 0.f;

    int wave = t >> 6, lane = t & 63;
    int n16 = lane & 15, quad = lane >> 4;
    size_t rowb = (size_t)b * SEQ;
    size_t vb0 = (size_t)(h * DK + n16) * ROWS + rowb;
    size_t vb1 = (size_t)(h * DK + 16 + n16) * ROWS + rowb;
    f32x4 oc0 = {0.f,0.f,0.f,0.f}, oc1 = {0.f,0.f,0.f,0.f};

    #pragma unroll 1
    for (int hbase = 0; hbase < E; hbase += 1024) {
        int hend = min(hbase + 1024, E);
        #pragma unroll 1
        for (int j4 = hbase + 4 * c; j4 < hend; j4 += 128) {
            uint2 su = *(const uint2*)&s3p[j4];
            float4 C4 = *(const float4*)&c3p[j4];
            float s0 = __uint_as_float(su.x << 16);
            float s1 = __uint_as_float(su.x & 0xFFFF0000u);
            float s2 = __uint_as_float(su.y << 16);
            float s3v = __uint_as_float(su.y & 0xFFFF0000u);
            float pq = (float)(i - j4) * linv;
            float p0, p1, p2, p3;
            { float dist = sqt(fmaxf((Lc - C4.x) * pq, 0.f));
              float eff = fmaxf(ex2(dist * gamma2), 1e-5f);
              p0 = (j4 + 0 < nj) ? ex2(s0 * eff) : 0.f; l2 += p0; }
            { float dist = sqt(fmaxf((Lc - C4.y) * (pq - linv), 0.f));
              float eff = fmaxf(ex2(dist * gamma2), 1e-5f);
              p1 = (j4 + 1 < nj) ? ex2(s1 * eff) : 0.f; l2 += p1; }
            { float dist = sqt(fmaxf((Lc - C4.z) * (pq - li2), 0.f));
              float eff = fmaxf(ex2(dist * gamma2), 1e-5f);
              p2 = (j4 + 2 < nj) ? ex2(s2 * eff) : 0.f; l2 += p2; }
            { float dist = sqt(fmaxf((Lc - C4.w) * (pq - li3), 0.f));
              float eff = fmaxf(ex2(dist * gamma2), 1e-5f);
              p3 = (j4 + 3 < nj) ? ex2(s3v * eff) : 0.f; l2 += p3; }
            uint2 st;
            st.x = cvtpk(p0, p1);
            st.y = cvtpk(p2, p3);
            *(uint2*)&Sr[sw8(j4 - hbase)] = st;
        }
        __syncthreads();
        int pend = min(hbase + 1024, njPad32);
        #pragma unroll 1
        for (int j0 = hbase + wave * 32; j0 < pend; j0 += 256) {
            short8 Ap = *(const short8*)&SBH[n16 * SRBH + sw8(j0 - hbase + quad * 8)];
            int jo = j0 + quad * 8;
            short8 Bh0 = *(const short8*)&VS[vb0 + jo];
            short8 Bh1 = *(const short8*)&VS[vb1 + jo];
            oc0 = MFMA_BF16(Ap, Bh0, oc0, 0, 0, 0);
            oc1 = MFMA_BF16(Ap, Bh1, oc1, 0, 0, 0);
        }
        __syncthreads();
    }

    l2 = red16(l2);
    l2 += swz_x16(l2);
    if (c == 0) l2inv_s[r] = (nj > 0) ? rcp(l2) : 0.f;
    float* FS = (float*)SBH;
    #pragma unroll
    for (int g = 0; g < 4; ++g) {
        int row = quad * 4 + g;
        FS[wave * 512 + row * 32 + n16] = oc0[g];
        FS[wave * 512 + row * 32 + 16 + n16] = oc1[g];
    }
    __syncthreads();
    {
        int r2 = t >> 5, d = t & 31;
        float sum = 0.f;
        #pragma unroll
        for (int w = 0; w < 8; ++w)
            sum += FS[w * 512 + r2 * 32 + d];
        O[base + (size_t)(i0 + r2) * DM + d] = sum * l2inv_s[r2];
    }
}

// ---------- final readout (f32 output), single-barrier beta reduction ------
__global__ __launch_bounds__(256) void readout_kernel(
    const float* __restrict__ h3, const float* __restrict__ qe,
    const float* __restrict__ key8,
    const float* __restrict__ lvW, const float* __restrict__ lvb,
    float* __restrict__ out)
{
    __shared__ float hrow[DM], qrow[DM];
    __shared__ float red8[4][NH];
    int n = blockIdx.x, t = threadIdx.x;
    int lane = t & 63, wid = t >> 6;
    hrow[t] = h3[(size_t)n * DM + t];
    qrow[t] = qe[(size_t)n * DM + t];
    __syncthreads();
    float ph[NH];
    #pragma unroll
    for (int h = 0; h < NH; ++h) {
        float v = key8[(size_t)h * DM + t] * qrow[t];
        v = waveRedSum(v);
        ph[h] = v;
    }
    if (lane == 0) {
        #pragma unroll
        for (int h = 0; h < NH; ++h) red8[wid][h] = ph[h];
    }
    __syncthreads();
    float beta[NH];
    #pragma unroll
    for (int h = 0; h < NH; ++h)
        beta[h] = red8[0][h] + red8[1][h] + red8[2][h] + red8[3][h];
    float bv = lvb[t];
    float vh[NH];
    for (int h = 0; h < NH; ++h) {
        float a = bv;
        #pragma unroll
        for (int c = 0; c < DK; ++c) a += hrow[h * DK + c] * lvW[(size_t)c * DM + t];
        vh[h] = 1.f / (1.f + __expf(-a));
    }
    float mb = beta[0];
    #pragma unroll
    for (int h = 1; h < NH; ++h) mb = fmaxf(mb, beta[h]);
    float se = 0.f, eh[NH];
    #pragma unroll
    for (int h = 0; h < NH; ++h) { eh[h] = __expf(beta[h] - mb); se += eh[h]; }
    float sinv = 1.f / se;
    float o = 0.f;
    #pragma unroll
    for (int h = 0; h < NH; ++h) o += eh[h] * sinv * vh[h];
    out[(size_t)n * DM + t] = o;
}

extern "C" void kernel_launch(void* const* d_in, const int* in_sizes, int n_in,
                              void* d_out, int out_size, void* d_ws, size_t ws_size,
                              hipStream_t stream) {
    (void)in_sizes; (void)n_in; (void)out_size; (void)ws_size;
    const float* q_emb  = (const float*)d_in[0];
    const float* qa_emb = (const float*)d_in[1];
    const float* b1_Wq = (const float*)d_in[2];
    const float* b1_bq = (const float*)d_in[3];
    const float* b1_Wv = (const float*)d_in[4];
    const float* b1_bv = (const float*)d_in[5];
    const float* b1_Wo = (const float*)d_in[6];
    const float* b1_bo = (const float*)d_in[7];
    const float* b1_gam = (const float*)d_in[8];
    const float* b1_lng = (const float*)d_in[9];
    const float* b1_lnb = (const float*)d_in[10];
    const float* b2_Wq = (const float*)d_in[11];
    const float* b2_bq = (const float*)d_in[12];
    const float* b2_Wv = (const float*)d_in[13];
    const float* b2_bv = (const float*)d_in[14];
    const float* b2_Wo = (const float*)d_in[15];
    const float* b2_bo = (const float*)d_in[16];
    const float* b2_gam = (const float*)d_in[17];
    const float* b2_lng = (const float*)d_in[18];
    const float* b2_lnb = (const float*)d_in[19];
    const float* b3_Wq = (const float*)d_in[20];
    const float* b3_bq = (const float*)d_in[21];
    const float* b3_Wk = (const float*)d_in[22];
    const float* b3_bk = (const float*)d_in[23];
    const float* b3_Wv = (const float*)d_in[24];
    const float* b3_bv = (const float*)d_in[25];
    const float* b3_Wo = (const float*)d_in[26];
    const float* b3_bo = (const float*)d_in[27];
    const float* b3_gam = (const float*)d_in[28];
    const float* b3_lng = (const float*)d_in[29];
    const float* b3_lnb = (const float*)d_in[30];
    const float* know  = (const float*)d_in[31];
    const float* lk_W  = (const float*)d_in[32];
    const float* lk_b  = (const float*)d_in[33];
    const float* lv_W  = (const float*)d_in[34];
    const float* lv_b  = (const float*)d_in[35];

    const size_t SLAB = (size_t)ROWS * DM;  // 1,048,576 floats = 4 MB
    const size_t USLAB = 2 * SLAB;          // split-bf16 buffer (hi+lo), ushorts
    float* A1 = (float*)d_ws;               // q1k1 f32; later k3
    float* A2 = A1 + SLAB;                  // q2k2 f32
    float* C1 = A2 + SLAB;                  // att1 out; later att3 out
    float* C2 = C1 + SLAB;                  // att2 out; later h3
    unsigned short* KS1 = (unsigned short*)(C2 + SLAB);  // later hq (f32)
    unsigned short* KS2 = KS1 + USLAB;                   // later ha (f32)
    unsigned short* VS1 = KS2 + USLAB;                   // later VS3 (hi only)
    unsigned short* VS2 = VS1 + USLAB;
    float* q3row = (float*)(VS2 + USLAB);   // 256
    float* key8  = q3row + DM;              // 8*256
    unsigned short* Wsp = (unsigned short*)(key8 + NH * DM);  // 9 x 256KB
    unsigned short* S3buf = Wsp + (size_t)9 * 131072;   // 16 x 2048 bf16
    float* C3buf = (float*)(S3buf + 16 * SEQ);          // 16 x 2048 f32
    float* Csum  = C3buf + 16 * SEQ;                    // 16 x 8 f32
    float* hq = (float*)KS1;
    float* ha = (float*)KS2;
    float* k3 = A1;
    unsigned short* VS3 = VS1;
    float* O3 = C1;
    float* h3 = C2;

    auto WH = [&](int i) { return Wsp + (size_t)i * 131072; };
    // 0:b1_Wq 1:b1_Wv 2:b1_Wo 3:b2_Wq 4:b2_Wv 5:b2_Wo 6:b3_Wk 7:b3_Wv 8:b3_Wo

    dim3 blk(256);
    dim3 ablk(512);
    dim3 agrid2(SEQ / RT, 32);        // dual-set attention (128 x 32)
    dim3 agrid1(SEQ / RT, 16);        // attn3 (128 x 16)
    dim3 rgrid(ROWS);

    // weights convert + (y==9) know/key8 precompute, one launch
    convert_w_kernel<<<dim3(64, 10), blk, 0, stream>>>(
        b1_Wq, b1_Wv, b1_Wo, b2_Wq, b2_Wv, b2_Wo, b3_Wk, b3_Wv, b3_Wo, Wsp,
        know, b3_Wq, b3_bq, lk_W, lk_b, q3row, key8);

    // ---- blocks 1+2 projections: q/k f32+rowsplit, v transposed hi-bf16 ----
    gemm4_kernel<<<dim3(ROWS/16, 4), blk, 0, stream>>>(
        q_emb,  WH(0), b1_bq, A1,      KS1,     nullptr,
        q_emb,  WH(1), b1_bv, nullptr, nullptr, VS1,
        qa_emb, WH(3), b2_bq, A2,      KS2,     nullptr,
        qa_emb, WH(4), b2_bv, nullptr, nullptr, VS2);

    // ---- blocks 1+2 attention (one dual-set launch) ----
    attn12_kernel<<<agrid2, ablk, 0, stream>>>(
        A1, KS1, VS1, b1_gam, C1,
        A2, KS2, VS2, b2_gam, C2);

    // ---- output projections + residual + LN (fused) -> hq, ha ----
    gemm_ln2_kernel<<<dim3(ROWS/16, 2), blk, 0, stream>>>(
        C1, WH(2), b1_bo, q_emb,  b1_lng, b1_lnb, hq, 0,
        C2, WH(5), b2_bo, qa_emb, b2_lng, b2_lnb, ha, 0);

    // ---- block 3: k3 = hq@W3k (f32), v3 = ha@W3v (transposed hi-bf16) ----
    gemm4_kernel<<<dim3(ROWS/16, 2), blk, 0, stream>>>(
        hq, WH(6), b3_bk, k3,      nullptr, nullptr,
        ha, WH(7), b3_bv, nullptr, nullptr, VS3,
        hq, WH(6), b3_bk, k3,      nullptr, nullptr,   // unused sets
        hq, WH(6), b3_bk, k3,      nullptr, nullptr);

    // ---- attn3 shared scores (parallel) + slice fix-up, then attention ----
    score3a_kernel<<<dim3(8, 16), blk, 0, stream>>>(q3row, k3, S3buf, C3buf, Csum);
    score3b_kernel<<<dim3(7, 16), blk, 0, stream>>>(Csum, C3buf);

    attn3_kernel<<<agrid1, ablk, 0, stream>>>(VS3, b3_gam, O3, S3buf, C3buf);

    // ---- y3 + know-residual + LN (fused) -> h3 ----
    gemm_ln2_kernel<<<dim3(ROWS/16, 1), blk, 0, stream>>>(
        O3, WH(8), b3_bo, know, b3_lng, b3_lnb, h3, 1,
        O3, WH(8), b3_bo, know, b3_lng, b3_lnb, h3, 1);

    readout_kernel<<<rgrid, blk, 0, stream>>>(h3, q_emb, key8, lv_W, lv_b,
                                              (float*)d_out);
}

// Round 11
// 419.818 us; speedup vs baseline: 1.0499x; 1.0499x over previous
//
#include <hip/hip_runtime.h>
#include <hip/hip_bf16.h>

#define DM 256
#define NH 8
#define DK 32
#define BSZ 2
#define SEQ 2048
#define ROWS (BSZ*SEQ)   // 4096
#define RT 16            // query rows per attention tile (full MFMA rows)
#define SRB 2312         // ushort row stride; swizzle phys = j + 8*(j>>6), max 2295

static __device__ __forceinline__ int sw8(int j) { return j + ((j >> 6) << 3); }

typedef __attribute__((ext_vector_type(8))) short short8;
typedef __attribute__((ext_vector_type(4))) float f32x4;

// f32 -> bf16 bits, round-to-nearest-even (validated r15)
static __device__ __forceinline__ unsigned short f2bf(float f) {
    unsigned u = __float_as_uint(f);
    return (unsigned short)((u + 0x7FFFu + ((u >> 16) & 1u)) >> 16);
}
static __device__ __forceinline__ float bf2f(unsigned short h) {
    return __uint_as_float(((unsigned)h) << 16);
}

// packed f32x2 -> bf16x2 (RNE), single HW instr — replaces 2x f2bf (6 VALU ops)
static __device__ __forceinline__ unsigned cvtpk(float lo, float hi) {
    unsigned r;
    asm("v_cvt_pk_bf16_f32 %0, %1, %2" : "=v"(r) : "v"(lo), "v"(hi));
    return r;
}

// native transcendentals: inputs are range-safe here (no denormal guard needed;
// underflow-to-zero is the desired semantics for exp2 of large-negative).
static __device__ __forceinline__ float ex2(float x) { return __builtin_amdgcn_exp2f(x); }
static __device__ __forceinline__ float sqt(float x) { return __builtin_amdgcn_sqrtf(x); }
static __device__ __forceinline__ float rcp(float x) { return __builtin_amdgcn_rcpf(x); }

// ---- DPP cross-lane (VALU-pipe, replaces ds_bpermute shuffles) ----
template<int CTRL, int RM>
static __device__ __forceinline__ float dppadd(float x) {
    int s = __builtin_amdgcn_update_dpp(0, __float_as_int(x), CTRL, RM, 0xf, true);
    return x + __int_as_float(s);
}
// inclusive prefix sum over each 32-lane group (lanes 0-31 / 32-63 independent)
static __device__ __forceinline__ float scan32(float x) {
    x = dppadd<0x111, 0xf>(x);   // row_shr:1
    x = dppadd<0x112, 0xf>(x);   // row_shr:2
    x = dppadd<0x114, 0xf>(x);   // row_shr:4
    x = dppadd<0x118, 0xf>(x);   // row_shr:8 -> per-16-row inclusive
    x = dppadd<0x142, 0xa>(x);   // row_bcast15, rows 1&3 only (mask 0xA)
    return x;
}
// sum over each 16-lane group, result in every lane
static __device__ __forceinline__ float red16(float x) {
    x = dppadd<0x0B1, 0xf>(x);   // quad_perm xor1
    x = dppadd<0x04E, 0xf>(x);   // quad_perm xor2
    x = dppadd<0x124, 0xf>(x);   // row_ror:4
    x = dppadd<0x128, 0xf>(x);   // row_ror:8
    return x;
}
// broadcast lane31 of each 32-group to all its lanes
static __device__ __forceinline__ float bcast31(float x) {
    return __int_as_float(__builtin_amdgcn_ds_swizzle(__float_as_int(x), 0x03E0));
}
// lane ^ 16 within each 32-group
static __device__ __forceinline__ float swz_x16(float x) {
    return __int_as_float(__builtin_amdgcn_ds_swizzle(__float_as_int(x), 0x401F));
}

// unpack 4 bf16 (from packed uint2) into f32
static __device__ __forceinline__ void unpack4(uint2 u, float& s0, float& s1,
                                               float& s2, float& s3) {
    s0 = __uint_as_float(u.x << 16);
    s1 = __uint_as_float(u.x & 0xFFFF0000u);
    s2 = __uint_as_float(u.y << 16);
    s3 = __uint_as_float(u.y & 0xFFFF0000u);
}

// decay+renorm for 4 consecutive cols; returns packed bf16 P. Serial in cum,
// but independent across calls — caller interleaves two for ILP.
static __device__ __forceinline__ uint2 decay_quad(
    float s0, float s1, float s2, float s3v,
    float e0, float e1, float e2, float e3,
    float cum, float pq, float linv,
    float l, float gamma2, float& l2)
{
    float p0, p1, p2, p3;
    cum += e0;
    { float dist = sqt(fmaxf((l - cum) * pq, 0.f));
      float eff = fmaxf(ex2(dist * gamma2), 1e-5f);
      p0 = ex2(s0 * eff); l2 += p0; }
    cum += e1;
    { float dist = sqt(fmaxf((l - cum) * (pq - linv), 0.f));
      float eff = fmaxf(ex2(dist * gamma2), 1e-5f);
      p1 = ex2(s1 * eff); l2 += p1; }
    cum += e2;
    { float dist = sqt(fmaxf((l - cum) * (pq - 2.f * linv), 0.f));
      float eff = fmaxf(ex2(dist * gamma2), 1e-5f);
      p2 = ex2(s2 * eff); l2 += p2; }
    cum += e3;
    { float dist = sqt(fmaxf((l - cum) * (pq - 3.f * linv), 0.f));
      float eff = fmaxf(ex2(dist * gamma2), 1e-5f);
      p3 = ex2(s3v * eff); l2 += p3; }
    uint2 st;
    st.x = cvtpk(p0, p1);
    st.y = cvtpk(p2, p3);
    return st;
}

#define MFMA_BF16 __builtin_amdgcn_mfma_f32_16x16x32_bf16
#define LOG2E 1.44269504088896340736f

// ---------- reduction helpers ----------
static __device__ __forceinline__ float waveRedSum(float v) {
    #pragma unroll
    for (int off = 32; off > 0; off >>= 1) v += __shfl_down(v, off, 64);
    return v;
}

// ---------- one-time: weights -> split-bf16, transposed [n][k] ------------
// blockIdx.y==9 (x==0) additionally runs the tiny know/key8 precompute,
// saving a separate serial launch.
__global__ __launch_bounds__(256) void convert_w_kernel(
    const float* __restrict__ S0, const float* __restrict__ S1, const float* __restrict__ S2,
    const float* __restrict__ S3, const float* __restrict__ S4, const float* __restrict__ S5,
    const float* __restrict__ S6, const float* __restrict__ S7, const float* __restrict__ S8,
    unsigned short* __restrict__ dst,
    const float* __restrict__ know,
    const float* __restrict__ W3q, const float* __restrict__ b3q,
    const float* __restrict__ lkW, const float* __restrict__ lkb,
    float* __restrict__ q3row, float* __restrict__ key8)
{
    __shared__ float kn[DM];
    int s = blockIdx.y;
    if (s == 9) {
        if (blockIdx.x != 0) return;
        int t = threadIdx.x;
        kn[t] = know[t];
        __syncthreads();
        float acc = b3q[t];
        for (int c = 0; c < DM; ++c) acc += kn[c] * W3q[(size_t)c * DM + t];
        q3row[t] = acc;
        float bk = lkb[t];
        for (int h = 0; h < NH; ++h) {
            float a = bk;
            #pragma unroll
            for (int c = 0; c < DK; ++c) a += kn[h * DK + c] * lkW[(size_t)c * DM + t];
            key8[(size_t)h * DM + t] = 1.f / (1.f + __expf(-a));
        }
        return;
    }
    const float* W;
    if (s == 0) W = S0; else if (s == 1) W = S1; else if (s == 2) W = S2;
    else if (s == 3) W = S3; else if (s == 4) W = S4; else if (s == 5) W = S5;
    else if (s == 6) W = S6; else if (s == 7) W = S7; else W = S8;
    unsigned short* H = dst + (size_t)s * 131072;
    unsigned short* L = H + 65536;

    int e = blockIdx.x * 1024 + threadIdx.x * 4;
    int k = e >> 8, n = e & 255;
    float4 w4 = *(const float4*)(W + e);
    float v[4] = {w4.x, w4.y, w4.z, w4.w};
    #pragma unroll
    for (int i = 0; i < 4; ++i) {
        unsigned short h = f2bf(v[i]);
        H[(size_t)(n + i) * 256 + k] = h;
        L[(size_t)(n + i) * 256 + k] = (unsigned short)f2bf(v[i] - bf2f(h));
    }
}

// ---------- batched MFMA GEMM (16x256/block, 4 sets) with optional ----------
// split-bf16 side outputs: KSo = [row][col] hi/lo; VSo = [col][row] hi only.
// VSo path stages the 16x256 tile in LDS and writes each column's 16 rows
// as 2x16B contiguous stores (4x wider than the old scattered ushort4).
__global__ __launch_bounds__(256) void gemm4_kernel(
    const float* __restrict__ X0, const unsigned short* __restrict__ H0, const float* __restrict__ B0,
    float* __restrict__ Y0, unsigned short* __restrict__ K0o, unsigned short* __restrict__ V0o,
    const float* __restrict__ X1, const unsigned short* __restrict__ H1, const float* __restrict__ B1,
    float* __restrict__ Y1, unsigned short* __restrict__ K1o, unsigned short* __restrict__ V1o,
    const float* __restrict__ X2, const unsigned short* __restrict__ H2, const float* __restrict__ B2,
    float* __restrict__ Y2, unsigned short* __restrict__ K2o, unsigned short* __restrict__ V2o,
    const float* __restrict__ X3, const unsigned short* __restrict__ H3, const float* __restrict__ B3,
    float* __restrict__ Y3, unsigned short* __restrict__ K3o, unsigned short* __restrict__ V3o)
{
    const float *X, *Bias; const unsigned short* H; float* Yf;
    unsigned short *KSo, *VSo;
    int s = blockIdx.y;
    if (s == 0)      { X = X0; H = H0; Bias = B0; Yf = Y0; KSo = K0o; VSo = V0o; }
    else if (s == 1) { X = X1; H = H1; Bias = B1; Yf = Y1; KSo = K1o; VSo = V1o; }
    else if (s == 2) { X = X2; H = H2; Bias = B2; Yf = Y2; KSo = K2o; VSo = V2o; }
    else             { X = X3; H = H3; Bias = B3; Yf = Y3; KSo = K3o; VSo = V3o; }
    const unsigned short* L = H + 65536;

    __shared__ __align__(16) unsigned short XhL[16 * 264];
    __shared__ __align__(16) unsigned short XlL[16 * 264];
    __shared__ __align__(16) unsigned short vt[256][24];   // V^T staging
    int t = threadIdx.x;
    int r0 = blockIdx.x * 16;
    {   // stage X tile as split bf16
        int r = t >> 4, c0 = (t & 15) * 16;
        const float* xp = X + (size_t)(r0 + r) * DM + c0;
        #pragma unroll
        for (int i = 0; i < 16; i += 4) {
            float4 v4 = *(const float4*)(xp + i);
            float vv[4] = {v4.x, v4.y, v4.z, v4.w};
            #pragma unroll
            for (int j = 0; j < 4; ++j) {
                unsigned short h = f2bf(vv[j]);
                XhL[r * 264 + c0 + i + j] = h;
                XlL[r * 264 + c0 + i + j] = (unsigned short)f2bf(vv[j] - bf2f(h));
            }
        }
    }
    __syncthreads();
    int lane = t & 63, wv = t >> 6;
    int m = lane & 15, quad = lane >> 4;
    f32x4 aa[4];
    #pragma unroll
    for (int nt = 0; nt < 4; ++nt) { aa[nt][0]=0.f; aa[nt][1]=0.f; aa[nt][2]=0.f; aa[nt][3]=0.f; }
    #pragma unroll 1
    for (int kc = 0; kc < 8; ++kc) {
        int k0 = kc * 32;
        short8 Ah = *(const short8*)&XhL[m * 264 + k0 + quad * 8];
        short8 Al = *(const short8*)&XlL[m * 264 + k0 + quad * 8];
        size_t boff = (size_t)(wv * 64 + m) * 256 + k0 + quad * 8;
        #pragma unroll
        for (int nt = 0; nt < 4; ++nt) {
            short8 Bh = *(const short8*)(H + boff + nt * 16 * 256);
            short8 Bl = *(const short8*)(L + boff + nt * 16 * 256);
            aa[nt] = MFMA_BF16(Al, Bh, aa[nt], 0, 0, 0);
            aa[nt] = MFMA_BF16(Ah, Bl, aa[nt], 0, 0, 0);
            aa[nt] = MFMA_BF16(Ah, Bh, aa[nt], 0, 0, 0);
        }
    }
    // epilogue: D col = lane&15 (+16*nt +64*wv), row = quad*4+g
    int col0 = wv * 64 + m;
    #pragma unroll
    for (int nt = 0; nt < 4; ++nt) {
        int col = col0 + nt * 16;
        float bb = Bias[col];
        float yv[4];
        #pragma unroll
        for (int g = 0; g < 4; ++g) yv[g] = aa[nt][g] + bb;
        if (Yf) {
            #pragma unroll
            for (int g = 0; g < 4; ++g)
                Yf[(size_t)(r0 + quad * 4 + g) * DM + col] = yv[g];
        }
        if (KSo) {
            unsigned short* KH = KSo;
            unsigned short* KL = KSo + (size_t)ROWS * DM;
            #pragma unroll
            for (int g = 0; g < 4; ++g) {
                unsigned short hb = f2bf(yv[g]);
                KH[(size_t)(r0 + quad * 4 + g) * DM + col] = hb;
                KL[(size_t)(r0 + quad * 4 + g) * DM + col] =
                    (unsigned short)f2bf(yv[g] - bf2f(hb));
            }
        }
        if (VSo) {
            ushort4 h4;
            h4.x = f2bf(yv[0]); h4.y = f2bf(yv[1]);
            h4.z = f2bf(yv[2]); h4.w = f2bf(yv[3]);
            *(ushort4*)&vt[col][quad * 4] = h4;
        }
    }
    if (VSo) {
        __syncthreads();
        short8 v0 = *(const short8*)&vt[t][0];
        short8 v1 = *(const short8*)&vt[t][8];
        unsigned short* vp = VSo + (size_t)t * ROWS + r0;
        *(short8*)vp = v0;
        *(short8*)(vp + 8) = v1;
    }
}

// ---------- MFMA GEMM + residual + LayerNorm fused (2 sets) ----------
__global__ __launch_bounds__(256) void gemm_ln2_kernel(
    const float* __restrict__ X0, const unsigned short* __restrict__ H0, const float* __restrict__ B0,
    const float* __restrict__ R0, const float* __restrict__ G0, const float* __restrict__ L0,
    float* __restrict__ Y0, int bc0,
    const float* __restrict__ X1, const unsigned short* __restrict__ H1, const float* __restrict__ B1,
    const float* __restrict__ R1, const float* __restrict__ G1, const float* __restrict__ L1,
    float* __restrict__ Y1, int bc1)
{
    const float *X, *Bias, *R, *G, *Lb; const unsigned short* H; float* Y; int bc;
    if (blockIdx.y == 0) { X=X0; H=H0; Bias=B0; R=R0; G=G0; Lb=L0; Y=Y0; bc=bc0; }
    else                 { X=X1; H=H1; Bias=B1; R=R1; G=G1; Lb=L1; Y=Y1; bc=bc1; }
    const unsigned short* L = H + 65536;

    __shared__ __align__(16) unsigned short XhL[16 * 264];
    __shared__ __align__(16) unsigned short XlL[16 * 264];
    __shared__ __align__(16) float yl[16 * 260];
    int t = threadIdx.x;
    int r0 = blockIdx.x * 16;
    {   int r = t >> 4, c0 = (t & 15) * 16;
        const float* xp = X + (size_t)(r0 + r) * DM + c0;
        #pragma unroll
        for (int i = 0; i < 16; i += 4) {
            float4 v4 = *(const float4*)(xp + i);
            float vv[4] = {v4.x, v4.y, v4.z, v4.w};
            #pragma unroll
            for (int j = 0; j < 4; ++j) {
                unsigned short h = f2bf(vv[j]);
                XhL[r * 264 + c0 + i + j] = h;
                XlL[r * 264 + c0 + i + j] = (unsigned short)f2bf(vv[j] - bf2f(h));
            }
        }
    }
    __syncthreads();
    int lane = t & 63, wv = t >> 6;
    int m = lane & 15, quad = lane >> 4;
    f32x4 aa[4];
    #pragma unroll
    for (int nt = 0; nt < 4; ++nt) { aa[nt][0]=0.f; aa[nt][1]=0.f; aa[nt][2]=0.f; aa[nt][3]=0.f; }
    #pragma unroll 1
    for (int kc = 0; kc < 8; ++kc) {
        int k0 = kc * 32;
        short8 Ah = *(const short8*)&XhL[m * 264 + k0 + quad * 8];
        short8 Al = *(const short8*)&XlL[m * 264 + k0 + quad * 8];
        size_t boff = (size_t)(wv * 64 + m) * 256 + k0 + quad * 8;
        #pragma unroll
        for (int nt = 0; nt < 4; ++nt) {
            short8 Bh = *(const short8*)(H + boff + nt * 16 * 256);
            short8 Bl = *(const short8*)(L + boff + nt * 16 * 256);
            aa[nt] = MFMA_BF16(Al, Bh, aa[nt], 0, 0, 0);
            aa[nt] = MFMA_BF16(Ah, Bl, aa[nt], 0, 0, 0);
            aa[nt] = MFMA_BF16(Ah, Bh, aa[nt], 0, 0, 0);
        }
    }
    {
        int col0 = wv * 64 + m;
        #pragma unroll
        for (int nt = 0; nt < 4; ++nt) {
            int col = col0 + nt * 16;
            float bb = Bias[col];
            #pragma unroll
            for (int g = 0; g < 4; ++g) {
                int row = quad * 4 + g;
                float res = bc ? R[col] : R[(size_t)(r0 + row) * DM + col];
                yl[row * 260 + col] = aa[nt][g] + bb + res;
            }
        }
    }
    __syncthreads();
    {
        int r = t >> 4, c0 = (t & 15) * 16;
        float vals[16];
        float part = 0.f;
        #pragma unroll
        for (int i = 0; i < 16; ++i) { vals[i] = yl[r * 260 + c0 + i]; part += vals[i]; }
        #pragma unroll
        for (int off = 8; off; off >>= 1) part += __shfl_xor(part, off, 16);
        float mean = part * (1.f / DM);
        float vp = 0.f;
        #pragma unroll
        for (int i = 0; i < 16; ++i) { float d = vals[i] - mean; vp += d * d; }
        #pragma unroll
        for (int off = 8; off; off >>= 1) vp += __shfl_xor(vp, off, 16);
        float rs = rsqrtf(vp * (1.f / DM) + 1e-5f);
        float* yp = Y + (size_t)(r0 + r) * DM + c0;
        #pragma unroll
        for (int i = 0; i < 16; i += 4) {
            float4 o;
            o.x = (vals[i+0] - mean) * rs * G[c0+i+0] + Lb[c0+i+0];
            o.y = (vals[i+1] - mean) * rs * G[c0+i+1] + Lb[c0+i+1];
            o.z = (vals[i+2] - mean) * rs * G[c0+i+2] + Lb[c0+i+2];
            o.w = (vals[i+3] - mean) * rs * G[c0+i+3] + Lb[c0+i+3];
            *(float4*)(yp + i) = o;
        }
    }
}

// ---------- attn3 scores, parallel: 128 blocks (8 j-slices x 16 bh) --------
__global__ __launch_bounds__(256) void score3a_kernel(
    const float* __restrict__ q3row, const float* __restrict__ K3,
    unsigned short* __restrict__ S3, float* __restrict__ C3,
    float* __restrict__ Csum)
{
    __shared__ float wsum[4];
    int s = blockIdx.x;            // j slice (0..7)
    int bh = blockIdx.y;           // b*8+h
    int b = bh >> 3, h = bh & 7;
    int t = threadIdx.x;
    int lane = t & 63, wv = t >> 6;
    int j = s * 256 + t;
    const float scaleL2 = 0.17677669529663687f * LOG2E;
    float qv[DK];
    #pragma unroll
    for (int d = 0; d < DK; d += 4) {
        float4 qq = *(const float4*)(q3row + h * DK + d);
        qv[d+0] = qq.x * scaleL2; qv[d+1] = qq.y * scaleL2;
        qv[d+2] = qq.z * scaleL2; qv[d+3] = qq.w * scaleL2;
    }
    const float* kp = K3 + ((size_t)b * SEQ + j) * DM + h * DK;
    float kv[DK];
    #pragma unroll
    for (int d = 0; d < DK; d += 4) {
        float4 kq = *(const float4*)(kp + d);
        kv[d+0] = kq.x; kv[d+1] = kq.y; kv[d+2] = kq.z; kv[d+3] = kq.w;
    }
    float sc = 0.f;
    #pragma unroll
    for (int d = 0; d < DK; ++d) sc += qv[d] * kv[d];
    unsigned short sb16 = f2bf(sc);
    float e = ex2(bf2f(sb16));
    float x = e;
    #pragma unroll
    for (int off = 1; off < 64; off <<= 1) {
        float y = __shfl_up(x, off, 64);
        if (lane >= off) x += y;
    }
    if (lane == 63) wsum[wv] = x;
    __syncthreads();
    float woff = 0.f;
    for (int w = 0; w < wv; ++w) woff += wsum[w];
    float inc = woff + x;
    S3[(size_t)bh * SEQ + j] = sb16;
    C3[(size_t)bh * SEQ + j] = inc;
    if (t == 255) Csum[bh * 8 + s] = inc;
}

// fix-up: add exclusive slice offsets so C3 is row-global inclusive.
__global__ __launch_bounds__(256) void score3b_kernel(
    const float* __restrict__ Csum, float* __restrict__ C3)
{
    int s = blockIdx.x + 1;        // slices 1..7
    int bh = blockIdx.y;
    int t = threadIdx.x;
    float off = 0.f;
    for (int w = 0; w < s; ++w) off += Csum[bh * 8 + w];
    C3[(size_t)bh * SEQ + s * 256 + t] += off;
}

// ---------- tiled attention with distance-decay bias ----------
// RT=16 + 512 threads. XCD-aware block swizzle (r7: FETCH 52->10 GB).
// r8: rotated prefetch in both pass-C loops — qbcast's s3p/c3p global loads
// (depth 2, ~200cy L2 latency hidden under decay chain) and the LDS score
// reads (depth 1). Pure reordering; numerics identical.
__global__ __launch_bounds__(512) void attn_tile_kernel(
    const float* __restrict__ Q0,
    const unsigned short* __restrict__ KS0, const unsigned short* __restrict__ VS0,
    const float* __restrict__ g0, float* __restrict__ O0,
    const float* __restrict__ Q1,
    const unsigned short* __restrict__ KS1, const unsigned short* __restrict__ VS1,
    const float* __restrict__ g1, float* __restrict__ O1,
    const unsigned short* __restrict__ S3g, const float* __restrict__ C3g,
    int peek, int qbcast)
{
    __shared__ __align__(16) unsigned short SB[RT * SRB];
    __shared__ float qs[RT][DK];
    __shared__ float l2inv_s[RT];
    __shared__ float rowsum[8 * RT];   // per-wave partial l (MFMA path)

    // XCD swizzle (gridDim.x == 128 for both launches)
    int bx, by;
    {
        int flat = (int)blockIdx.y * 128 + (int)blockIdx.x;
        int per = ((int)gridDim.y * 128) >> 3;     // blocks per XCD
        int nf = (flat & 7) * per + (flat >> 3);
        by = nf >> 7;
        bx = nf & 127;
    }
    int y = by;
    int set = y >> 4, bh = y & 15;
    const float* Q = set ? Q1 : Q0;
    const unsigned short* KS = set ? KS1 : KS0;
    const unsigned short* VS = set ? VS1 : VS0;
    const float* gm = set ? g1 : g0;
    float* O = set ? O1 : O0;

    int b = bh >> 3, h = bh & 7;
    int i0 = (127 - bx) * RT;          // largest-first within each XCD
    int t = threadIdx.x;
    size_t base = ((size_t)b * SEQ) * DM + (size_t)h * DK;

    int njAll = peek ? (i0 + RT) : (i0 + RT - 1);  // >= 15 always
    int njPad32 = (njAll + 31) & ~31;
    int njPad128 = (njAll + 127) & ~127;           // pass-C extent
    const float scaleL2 = 0.17677669529663687f * LOG2E;   // 1/sqrt(32)*log2e

    if (!qbcast) {
        {   // load Q tile (512 threads = 16 rows x 32)
            int r = t >> 5, d = t & 31;
            qs[r][d] = Q[base + (size_t)(i0 + r) * DM + d];
        }
        __syncthreads();

        // ---- Phase 1: 2-MFMA scores + fused per-row exp2 partial sums.
        {
            int wave = t >> 6, lane = t & 63;
            int m = lane & 15, quad = lane >> 4;

            float av[8];
            {
                float4 qa = *(const float4*)&qs[m][8 * quad];
                float4 qb = *(const float4*)&qs[m][8 * quad + 4];
                av[0]=qa.x*scaleL2; av[1]=qa.y*scaleL2; av[2]=qa.z*scaleL2; av[3]=qa.w*scaleL2;
                av[4]=qb.x*scaleL2; av[5]=qb.y*scaleL2; av[6]=qb.z*scaleL2; av[7]=qb.w*scaleL2;
            }
            short8 Ah;
            #pragma unroll
            for (int i = 0; i < 8; ++i) Ah[i] = (short)f2bf(av[i]);

            const unsigned short* KH = KS;
            const unsigned short* KL = KS + (size_t)ROWS * DM;
            size_t rowb = (size_t)b * SEQ;
            int njr0 = i0 + quad * 4 + peek;      // nj of row quad*4
            float rp0 = 0.f, rp1 = 0.f, rp2 = 0.f, rp3 = 0.f;
            int nChunks = (njAll + 15) >> 4;
            #pragma unroll 2
            for (int c = wave; c < nChunks; c += 8) {
                int j0 = c << 4;
                size_t off = (rowb + j0 + m) * DM + h * DK + quad * 8;
                short8 Bh = *(const short8*)&KH[off];
                short8 Bl = *(const short8*)&KL[off];
                f32x4 acc = {0.f, 0.f, 0.f, 0.f};
                acc = MFMA_BF16(Ah, Bl, acc, 0, 0, 0);
                acc = MFMA_BF16(Ah, Bh, acc, 0, 0, 0);
                int jcol = j0 + m;
                int sj = sw8(jcol);
                unsigned pk01 = cvtpk(acc[0], acc[1]);
                unsigned pk23 = cvtpk(acc[2], acc[3]);
                SB[(quad * 4 + 0) * SRB + sj] = (unsigned short)pk01;
                SB[(quad * 4 + 1) * SRB + sj] = (unsigned short)(pk01 >> 16);
                SB[(quad * 4 + 2) * SRB + sj] = (unsigned short)pk23;
                SB[(quad * 4 + 3) * SRB + sj] = (unsigned short)(pk23 >> 16);
                rp0 += (jcol < njr0 + 0) ? ex2(acc[0]) : 0.f;
                rp1 += (jcol < njr0 + 1) ? ex2(acc[1]) : 0.f;
                rp2 += (jcol < njr0 + 2) ? ex2(acc[2]) : 0.f;
                rp3 += (jcol < njr0 + 3) ? ex2(acc[3]) : 0.f;
            }
            rp0 = red16(rp0); rp1 = red16(rp1);
            rp2 = red16(rp2); rp3 = red16(rp3);
            if (m == 0) {
                rowsum[wave * RT + quad * 4 + 0] = rp0;
                rowsum[wave * RT + quad * 4 + 1] = rp1;
                rowsum[wave * RT + quad * 4 + 2] = rp2;
                rowsum[wave * RT + quad * 4 + 3] = rp3;
            }
        }
        __syncthreads();

        // ---- Tail fill: bf16 -inf into [nj_r, njPad128) per row ----
        {
            int r = t >> 5, c = t & 31;
            int i = i0 + r;
            int nj = peek ? (i + 1) : i;
            for (int j = nj + c; j < njPad128; j += 32)
                SB[r * SRB + sw8(j)] = 0xFF80u;   // bf16 -inf
        }
        __syncthreads();
    }

    // ---- Pass C ----
    if (qbcast) {
        int r = t >> 5, c = t & 31;
        int i = i0 + r;
        int nj = peek ? (i + 1) : i;
        unsigned short* Sr = SB + r * SRB;
        float gamma2 = -log1pf(__expf(gm[h])) * LOG2E;
        const unsigned short* s3p = S3g + (size_t)bh * SEQ;
        const float* c3p = C3g + (size_t)bh * SEQ;
        float Lc = (nj > 0) ? c3p[nj - 1] : 0.f;
        float linv = (nj > 0) ? rcp(Lc) : 0.f;
        float li2 = linv + linv, li3 = li2 + linv;
        float l2 = 0.f;
        int nIt = (njPad32 + 127) >> 7;
        int j4 = 4 * c;
        // depth-2 rotated prefetch (clamped to row end -> always in-bounds)
        uint2 su_a = *(const uint2*)&s3p[j4];
        float4 C4_a = *(const float4*)&c3p[j4];
        int jp = (j4 + 128 < SEQ - 3) ? j4 + 128 : SEQ - 4;
        uint2 su_b = *(const uint2*)&s3p[jp];
        float4 C4_b = *(const float4*)&c3p[jp];
        #pragma unroll 1
        for (int k = 0; k < nIt; ++k, j4 += 128) {
            uint2 su = su_a; float4 C4 = C4_a;
            su_a = su_b; C4_a = C4_b;
            int jn = (j4 + 256 < SEQ - 3) ? j4 + 256 : SEQ - 4;
            su_b = *(const uint2*)&s3p[jn];
            C4_b = *(const float4*)&c3p[jn];
            float s0 = __uint_as_float(su.x << 16);
            float s1 = __uint_as_float(su.x & 0xFFFF0000u);
            float s2 = __uint_as_float(su.y << 16);
            float s3v = __uint_as_float(su.y & 0xFFFF0000u);
            float pq = (float)(i - j4) * linv;
            float p0, p1, p2, p3;
            { float dist = sqt(fmaxf((Lc - C4.x) * pq, 0.f));
              float eff = fmaxf(ex2(dist * gamma2), 1e-5f);
              p0 = (j4 + 0 < nj) ? ex2(s0 * eff) : 0.f; l2 += p0; }
            { float dist = sqt(fmaxf((Lc - C4.y) * (pq - linv), 0.f));
              float eff = fmaxf(ex2(dist * gamma2), 1e-5f);
              p1 = (j4 + 1 < nj) ? ex2(s1 * eff) : 0.f; l2 += p1; }
            { float dist = sqt(fmaxf((Lc - C4.z) * (pq - li2), 0.f));
              float eff = fmaxf(ex2(dist * gamma2), 1e-5f);
              p2 = (j4 + 2 < nj) ? ex2(s2 * eff) : 0.f; l2 += p2; }
            { float dist = sqt(fmaxf((Lc - C4.w) * (pq - li3), 0.f));
              float eff = fmaxf(ex2(dist * gamma2), 1e-5f);
              p3 = (j4 + 3 < nj) ? ex2(s3v * eff) : 0.f; l2 += p3; }
            uint2 st;
            st.x = cvtpk(p0, p1);
            st.y = cvtpk(p2, p3);
            *(uint2*)&Sr[sw8(j4)] = st;
        }
        l2 = red16(l2);
        l2 += swz_x16(l2);
        if (c == 0) l2inv_s[r] = (nj > 0) ? rcp(l2) : 0.f;
    } else {
        int r = t >> 5, c = t & 31;
        int i = i0 + r;
        int nj = peek ? (i + 1) : i;
        unsigned short* Sr = SB + r * SRB;
        float gamma2 = -log1pf(__expf(gm[h])) * LOG2E;

        float l = 0.f;
        #pragma unroll
        for (int w = 0; w < 8; ++w) l += rowsum[w * RT + r];
        float linv = rcp(l);

        float l2 = 0.f;
        float Bc = 0.f;      // RAW cumulative (un-normalized)
        int nIter = (njPad32 + 127) >> 7;   // 128-col sub-iterations (uniform)
        int pairs = nIter >> 1;
        // depth-1 rotated LDS prefetch (next reads stay within LDS alloc)
        uint2 nxA, nxB;
        nxA = *(const uint2*)&Sr[sw8(4 * c)];
        nxB = *(const uint2*)&Sr[sw8(4 * c + 128)];
        #pragma unroll 1
        for (int k = 0; k < pairs; ++k) {
            int j4a = 256 * k + 4 * c;
            int j4b = j4a + 128;
            uint2 uA = nxA;
            uint2 uB = nxB;
            nxA = *(const uint2*)&Sr[sw8(j4a + 256)];
            nxB = *(const uint2*)&Sr[sw8(j4b + 256)];
            float a0, a1, a2, a3, b0, b1, b2, b3;
            unpack4(uA, a0, a1, a2, a3);
            unpack4(uB, b0, b1, b2, b3);
            float eA0 = ex2(a0), eA1 = ex2(a1), eA2 = ex2(a2), eA3 = ex2(a3);
            float eB0 = ex2(b0), eB1 = ex2(b1), eB2 = ex2(b2), eB3 = ex2(b3);
            float sigA = eA0 + eA1 + eA2 + eA3;
            float sigB = eB0 + eB1 + eB2 + eB3;
            float xA = scan32(sigA);        // independent scans -> 2x ILP
            float xB = scan32(sigB);
            float totA = bcast31(xA);       // two ds_swizzles pipeline
            float totB = bcast31(xB);
            float cumA = Bc + (xA - sigA);
            float cumB = Bc + totA + (xB - sigB);
            Bc += totA + totB;
            float pqA = (float)(i - j4a) * linv;
            float pqB = pqA - 128.f * linv;
            uint2 stA = decay_quad(a0, a1, a2, a3, eA0, eA1, eA2, eA3,
                                   cumA, pqA, linv, l, gamma2, l2);
            uint2 stB = decay_quad(b0, b1, b2, b3, eB0, eB1, eB2, eB3,
                                   cumB, pqB, linv, l, gamma2, l2);
            *(uint2*)&Sr[sw8(j4a)] = stA;
            *(uint2*)&Sr[sw8(j4b)] = stB;
        }
        if (nIter & 1) {
            int j4a = 256 * pairs + 4 * c;
            uint2 uA = nxA;                 // == Sr[sw8(j4a)] (pairs>0); pairs==0 -> prologue load
            float a0, a1, a2, a3;
            unpack4(uA, a0, a1, a2, a3);
            float eA0 = ex2(a0), eA1 = ex2(a1), eA2 = ex2(a2), eA3 = ex2(a3);
            float sigA = eA0 + eA1 + eA2 + eA3;
            float xA = scan32(sigA);
            float cumA = Bc + (xA - sigA);
            float pqA = (float)(i - j4a) * linv;
            uint2 stA = decay_quad(a0, a1, a2, a3, eA0, eA1, eA2, eA3,
                                   cumA, pqA, linv, l, gamma2, l2);
            *(uint2*)&Sr[sw8(j4a)] = stA;
        }
        l2 = red16(l2);
        l2 += swz_x16(l2);
        if (c == 0) l2inv_s[r] = (nj > 0) ? rcp(l2) : 0.f;
    }
    __syncthreads();

    // ---- Phase 5 PV: MFMA, P bf16 in SB (A), V hi-only (B).
    {
        int wave = t >> 6, lane = t & 63;
        int n16 = lane & 15, quad = lane >> 4;
        const unsigned short* VH = VS;
        size_t vb0 = (size_t)(h * DK + n16) * ROWS + (size_t)b * SEQ;
        size_t vb1 = (size_t)(h * DK + 16 + n16) * ROWS + (size_t)b * SEQ;
        f32x4 oc0 = {0.f,0.f,0.f,0.f}, oc1 = {0.f,0.f,0.f,0.f};
        #pragma unroll 2
        for (int j0 = wave * 32; j0 < njPad32; j0 += 256) {
            short8 Ap = *(const short8*)&SB[n16 * SRB + sw8(j0 + quad * 8)];
            int jo = j0 + quad * 8;
            short8 Bh0 = *(const short8*)&VH[vb0 + jo];
            short8 Bh1 = *(const short8*)&VH[vb1 + jo];
            oc0 = MFMA_BF16(Ap, Bh0, oc0, 0, 0, 0);
            oc1 = MFMA_BF16(Ap, Bh1, oc1, 0, 0, 0);
        }
        __syncthreads();          // packed fully consumed -> reuse SB as f32
        float* FS = (float*)SB;
        {
            #pragma unroll
            for (int g = 0; g < 4; ++g) {
                int row = quad * 4 + g;
                FS[wave * 512 + row * 32 + n16] = oc0[g];
                FS[wave * 512 + row * 32 + 16 + n16] = oc1[g];
            }
        }
    }
    __syncthreads();
    {
        float* FS = (float*)SB;
        int r2 = t >> 5, d = t & 31;
        float sum = 0.f;
        #pragma unroll
        for (int w = 0; w < 8; ++w)
            sum += FS[w * 512 + r2 * 32 + d];
        int ii = i0 + r2;
        O[base + (size_t)ii * DM + d] = sum * l2inv_s[r2];
    }
}

// ---------- final readout (f32 output), single-barrier beta reduction ------
__global__ __launch_bounds__(256) void readout_kernel(
    const float* __restrict__ h3, const float* __restrict__ qe,
    const float* __restrict__ key8,
    const float* __restrict__ lvW, const float* __restrict__ lvb,
    float* __restrict__ out)
{
    __shared__ float hrow[DM], qrow[DM];
    __shared__ float red8[4][NH];
    int n = blockIdx.x, t = threadIdx.x;
    int lane = t & 63, wid = t >> 6;
    hrow[t] = h3[(size_t)n * DM + t];
    qrow[t] = qe[(size_t)n * DM + t];
    __syncthreads();
    float ph[NH];
    #pragma unroll
    for (int h = 0; h < NH; ++h) {
        float v = key8[(size_t)h * DM + t] * qrow[t];
        v = waveRedSum(v);
        ph[h] = v;
    }
    if (lane == 0) {
        #pragma unroll
        for (int h = 0; h < NH; ++h) red8[wid][h] = ph[h];
    }
    __syncthreads();
    float beta[NH];
    #pragma unroll
    for (int h = 0; h < NH; ++h)
        beta[h] = red8[0][h] + red8[1][h] + red8[2][h] + red8[3][h];
    float bv = lvb[t];
    float vh[NH];
    for (int h = 0; h < NH; ++h) {
        float a = bv;
        #pragma unroll
        for (int c = 0; c < DK; ++c) a += hrow[h * DK + c] * lvW[(size_t)c * DM + t];
        vh[h] = 1.f / (1.f + __expf(-a));
    }
    float mb = beta[0];
    #pragma unroll
    for (int h = 1; h < NH; ++h) mb = fmaxf(mb, beta[h]);
    float se = 0.f, eh[NH];
    #pragma unroll
    for (int h = 0; h < NH; ++h) { eh[h] = __expf(beta[h] - mb); se += eh[h]; }
    float sinv = 1.f / se;
    float o = 0.f;
    #pragma unroll
    for (int h = 0; h < NH; ++h) o += eh[h] * sinv * vh[h];
    out[(size_t)n * DM + t] = o;
}

extern "C" void kernel_launch(void* const* d_in, const int* in_sizes, int n_in,
                              void* d_out, int out_size, void* d_ws, size_t ws_size,
                              hipStream_t stream) {
    (void)in_sizes; (void)n_in; (void)out_size; (void)ws_size;
    const float* q_emb  = (const float*)d_in[0];
    const float* qa_emb = (const float*)d_in[1];
    const float* b1_Wq = (const float*)d_in[2];
    const float* b1_bq = (const float*)d_in[3];
    const float* b1_Wv = (const float*)d_in[4];
    const float* b1_bv = (const float*)d_in[5];
    const float* b1_Wo = (const float*)d_in[6];
    const float* b1_bo = (const float*)d_in[7];
    const float* b1_gam = (const float*)d_in[8];
    const float* b1_lng = (const float*)d_in[9];
    const float* b1_lnb = (const float*)d_in[10];
    const float* b2_Wq = (const float*)d_in[11];
    const float* b2_bq = (const float*)d_in[12];
    const float* b2_Wv = (const float*)d_in[13];
    const float* b2_bv = (const float*)d_in[14];
    const float* b2_Wo = (const float*)d_in[15];
    const float* b2_bo = (const float*)d_in[16];
    const float* b2_gam = (const float*)d_in[17];
    const float* b2_lng = (const float*)d_in[18];
    const float* b2_lnb = (const float*)d_in[19];
    const float* b3_Wq = (const float*)d_in[20];
    const float* b3_bq = (const float*)d_in[21];
    const float* b3_Wk = (const float*)d_in[22];
    const float* b3_bk = (const float*)d_in[23];
    const float* b3_Wv = (const float*)d_in[24];
    const float* b3_bv = (const float*)d_in[25];
    const float* b3_Wo = (const float*)d_in[26];
    const float* b3_bo = (const float*)d_in[27];
    const float* b3_gam = (const float*)d_in[28];
    const float* b3_lng = (const float*)d_in[29];
    const float* b3_lnb = (const float*)d_in[30];
    const float* know  = (const float*)d_in[31];
    const float* lk_W  = (const float*)d_in[32];
    const float* lk_b  = (const float*)d_in[33];
    const float* lv_W  = (const float*)d_in[34];
    const float* lv_b  = (const float*)d_in[35];

    const size_t SLAB = (size_t)ROWS * DM;  // 1,048,576 floats = 4 MB
    const size_t USLAB = 2 * SLAB;          // split-bf16 buffer (hi+lo), ushorts
    float* A1 = (float*)d_ws;               // q1k1 f32; later k3
    float* A2 = A1 + SLAB;                  // q2k2 f32
    float* C1 = A2 + SLAB;                  // att1 out; later att3 out
    float* C2 = C1 + SLAB;                  // att2 out; later h3
    unsigned short* KS1 = (unsigned short*)(C2 + SLAB);  // later hq (f32)
    unsigned short* KS2 = KS1 + USLAB;                   // later ha (f32)
    unsigned short* VS1 = KS2 + USLAB;                   // later VS3 (hi only)
    unsigned short* VS2 = VS1 + USLAB;
    float* q3row = (float*)(VS2 + USLAB);   // 256
    float* key8  = q3row + DM;              // 8*256
    unsigned short* Wsp = (unsigned short*)(key8 + NH * DM);  // 9 x 256KB
    unsigned short* S3buf = Wsp + (size_t)9 * 131072;   // 16 x 2048 bf16
    float* C3buf = (float*)(S3buf + 16 * SEQ);          // 16 x 2048 f32
    float* Csum  = C3buf + 16 * SEQ;                    // 16 x 8 f32
    float* hq = (float*)KS1;
    float* ha = (float*)KS2;
    float* k3 = A1;
    unsigned short* VS3 = VS1;
    float* O3 = C1;
    float* h3 = C2;

    auto WH = [&](int i) { return Wsp + (size_t)i * 131072; };
    // 0:b1_Wq 1:b1_Wv 2:b1_Wo 3:b2_Wq 4:b2_Wv 5:b2_Wo 6:b3_Wk 7:b3_Wv 8:b3_Wo

    dim3 blk(256);
    dim3 ablk(512);
    dim3 agrid2(SEQ / RT, 32);        // dual-set attention (128 x 32)
    dim3 agrid1(SEQ / RT, 16);        // single-set attention
    dim3 rgrid(ROWS);

    // weights convert + (y==9) know/key8 precompute, one launch
    convert_w_kernel<<<dim3(64, 10), blk, 0, stream>>>(
        b1_Wq, b1_Wv, b1_Wo, b2_Wq, b2_Wv, b2_Wo, b3_Wk, b3_Wv, b3_Wo, Wsp,
        know, b3_Wq, b3_bq, lk_W, lk_b, q3row, key8);

    // ---- blocks 1+2 projections: q/k f32+rowsplit, v transposed hi-bf16 ----
    gemm4_kernel<<<dim3(ROWS/16, 4), blk, 0, stream>>>(
        q_emb,  WH(0), b1_bq, A1,      KS1,     nullptr,
        q_emb,  WH(1), b1_bv, nullptr, nullptr, VS1,
        qa_emb, WH(3), b2_bq, A2,      KS2,     nullptr,
        qa_emb, WH(4), b2_bv, nullptr, nullptr, VS2);

    // ---- blocks 1+2 attention (one dual-set launch) ----
    attn_tile_kernel<<<agrid2, ablk, 0, stream>>>(
        A1, KS1, VS1, b1_gam, C1,
        A2, KS2, VS2, b2_gam, C2,
        nullptr, nullptr, 1, 0);

    // ---- output projections + residual + LN (fused) -> hq, ha ----
    gemm_ln2_kernel<<<dim3(ROWS/16, 2), blk, 0, stream>>>(
        C1, WH(2), b1_bo, q_emb,  b1_lng, b1_lnb, hq, 0,
        C2, WH(5), b2_bo, qa_emb, b2_lng, b2_lnb, ha, 0);

    // ---- block 3: k3 = hq@W3k (f32), v3 = ha@W3v (transposed hi-bf16) ----
    gemm4_kernel<<<dim3(ROWS/16, 2), blk, 0, stream>>>(
        hq, WH(6), b3_bk, k3,      nullptr, nullptr,
        ha, WH(7), b3_bv, nullptr, nullptr, VS3,
        hq, WH(6), b3_bk, k3,      nullptr, nullptr,   // unused sets
        hq, WH(6), b3_bk, k3,      nullptr, nullptr);

    // ---- attn3 shared scores (parallel) + slice fix-up, then attention ----
    score3a_kernel<<<dim3(8, 16), blk, 0, stream>>>(q3row, k3, S3buf, C3buf, Csum);
    score3b_kernel<<<dim3(7, 16), blk, 0, stream>>>(Csum, C3buf);

    attn_tile_kernel<<<agrid1, ablk, 0, stream>>>(
        q3row, nullptr, VS3, b3_gam, O3,
        q3row, nullptr, VS3, b3_gam, O3,
        S3buf, C3buf, 0, 1);

    // ---- y3 + know-residual + LN (fused) -> h3 ----
    gemm_ln2_kernel<<<dim3(ROWS/16, 1), blk, 0, stream>>>(
        O3, WH(8), b3_bo, know, b3_lng, b3_lnb, h3, 1,
        O3, WH(8), b3_bo, know, b3_lng, b3_lnb, h3, 1);

    readout_kernel<<<rgrid, blk, 0, stream>>>(h3, q_emb, key8, lv_W, lv_b,
                                              (float*)d_out);
}